// Round 2
// baseline (1493.326 us; speedup 1.0000x reference)
//
#include <hip/hip_runtime.h>
#include <hip/hip_bf16.h>
#include <stdint.h>

// ConditionalLoRALinear: out = x@W^T + b + mask*(2*(x@A^T)@B^T)
// M=16384 (B*S), K=4096, N=4096, R=8. bf16 MFMA path (threshold allows bf16 floor).
// R2: fragment-major LDS (zero-conflict lane-linear ds_read_b128) + double-buffered
//     single-barrier K-loop (stage(t+1) overlaps MFMA(t)).

typedef __attribute__((ext_vector_type(8))) __bf16 bf16x8;
typedef __attribute__((ext_vector_type(4))) float f32x4;

#define M_DIM 16384
#define K_DIM 4096
#define N_DIM 4096
#define BM 128
#define BN 128
#define BK 64

// ---------------- f32 -> bf16 conversion (vectorized, grid-stride) ----------------
__global__ void cvt_f32_bf16(const float* __restrict__ in, __hip_bfloat16* __restrict__ out, int n8) {
    int i = blockIdx.x * blockDim.x + threadIdx.x;
    int stride = gridDim.x * blockDim.x;
    for (; i < n8; i += stride) {
        const float4* p = (const float4*)(in + (size_t)i * 8);
        float4 v0 = p[0], v1 = p[1];
        bf16x8 o;
        o[0] = (__bf16)v0.x; o[1] = (__bf16)v0.y; o[2] = (__bf16)v0.z; o[3] = (__bf16)v0.w;
        o[4] = (__bf16)v1.x; o[5] = (__bf16)v1.y; o[6] = (__bf16)v1.z; o[7] = (__bf16)v1.w;
        *(bf16x8*)((__hip_bfloat16*)out + (size_t)i * 8) = o;
    }
}

// ---------------- xa[m][r] = SCALING * mask(m) * dot(x[m], A[r]) ----------------
__global__ void compute_xa(const __hip_bfloat16* __restrict__ Xb,
                           const int* __restrict__ ids,
                           const float* __restrict__ A,   // [8, K]
                           float* __restrict__ xa) {
    int t = threadIdx.x;
    int r = t & 63;
    int kq = t >> 6;
    int row = blockIdx.x * 64 + r;
    const __hip_bfloat16* xrow = Xb + (size_t)row * K_DIM + kq * 1024;
    float acc[8] = {0.f, 0.f, 0.f, 0.f, 0.f, 0.f, 0.f, 0.f};
    for (int i = 0; i < 128; i++) {
        bf16x8 xv = *(const bf16x8*)(xrow + i * 8);
        int kk = kq * 1024 + i * 8;   // wave-uniform
#pragma unroll
        for (int rr = 0; rr < 8; rr++) {
            const float* ap = A + rr * K_DIM + kk;
            float4 a0 = *(const float4*)ap;
            float4 a1 = *(const float4*)(ap + 4);
            acc[rr] += (float)xv[0] * a0.x + (float)xv[1] * a0.y + (float)xv[2] * a0.z + (float)xv[3] * a0.w
                     + (float)xv[4] * a1.x + (float)xv[5] * a1.y + (float)xv[6] * a1.z + (float)xv[7] * a1.w;
        }
    }
    __shared__ float red[4][64][8];
#pragma unroll
    for (int rr = 0; rr < 8; rr++) red[kq][r][rr] = acc[rr];
    __syncthreads();
    if (t < 64) {
        int rowg = blockIdx.x * 64 + t;
        float gate = (ids[rowg] == 7) ? 2.0f : 0.0f;
#pragma unroll
        for (int rr = 0; rr < 8; rr++) {
            float s = (red[0][t][rr] + red[1][t][rr]) + (red[2][t][rr] + red[3][t][rr]);
            xa[(size_t)rowg * 8 + rr] = s * gate;
        }
    }
}

// ---------------- main GEMM: out = Xb @ Wb^T + bias + xa @ loraB^T ----------------
// 128x128 tile, BK=64, 4 waves (2x2), 4x4 frags of 16x16x32 bf16/wave.
// LDS is FRAGMENT-MAJOR: tile = 16 chunks of 1 KiB; chunk c = g*2+ks holds, at
// lane*16, the bytes A[g*16 + (lane&15)][k0 + ks*32 + (lane>>4)*8 .. +8].
// ds_read_b128 is then base + lane*16 (zero bank conflicts); the per-lane global
// source address implements the permutation (rule #21: swizzle-on-source).
__device__ __forceinline__ void gload_lds16(const void* g, void* l) {
    __builtin_amdgcn_global_load_lds(
        (const __attribute__((address_space(1))) unsigned int*)g,
        (__attribute__((address_space(3))) unsigned int*)l, 16, 0, 0);
}

__global__ __launch_bounds__(256) void gemm_bias_lora(
    const __hip_bfloat16* __restrict__ Xb,   // [M, K]
    const __hip_bfloat16* __restrict__ Wb,   // [N, K]
    const float* __restrict__ bias,          // [N]
    const float* __restrict__ xa,            // [M, 8] pre-scaled & gated
    const float* __restrict__ loraB,         // [N, 8]
    float* __restrict__ out) {
    __shared__ __hip_bfloat16 As[2][BM * BK];   // 2 x 16 KiB
    __shared__ __hip_bfloat16 Bs[2][BN * BK];   // 2 x 16 KiB

    int tid = threadIdx.x;
    int bid = blockIdx.x;
    int n_tile = bid & 31;        // N/BN = 32
    int m_tile = bid >> 5;        // M/BM = 128
    int m_base = m_tile * BM, n_base = n_tile * BN;
    int wave = tid >> 6, lane = tid & 63;
    int wr = wave >> 1, wc = wave & 1;
    int l15 = lane & 15, lhi = lane >> 4;

    f32x4 acc[4][4] = {};

    const char* Abase = (const char*)(Xb + (size_t)m_base * K_DIM);
    const char* Bbase = (const char*)(Wb + (size_t)n_base * K_DIM);

    // per-thread staging constants: this wave stages chunks c = wave*4 .. wave*4+3
    // chunk c: g = c>>1 (row-group of 16), ks = c&1 (k-half of 32 elems)
    auto stage = [&](int k0, int buf) {
        char* as = (char*)&As[buf][0];
        char* bs = (char*)&Bs[buf][0];
#pragma unroll
        for (int i = 0; i < 4; i++) {
            int c = wave * 4 + i;
            int g = c >> 1, ks = c & 1;
            int row = g * 16 + l15;
            size_t gsrc = (size_t)row * (K_DIM * 2) + (size_t)k0 * 2 + ks * 64 + lhi * 16;
            int ldst = c * 1024 + lane * 16;
            gload_lds16(Abase + gsrc, as + ldst);
            gload_lds16(Bbase + gsrc, bs + ldst);
        }
    };

    stage(0, 0);
    __syncthreads();                      // buf0 ready (vmcnt(0) auto-drained)

    int cur = 0;
    const int NT = K_DIM / BK;            // 64
    for (int t = 0; t < NT; t++) {
        if (t + 1 < NT) stage((t + 1) * BK, cur ^ 1);   // overlap with MFMA below
        const char* as = (const char*)&As[cur][0];
        const char* bs = (const char*)&Bs[cur][0];
#pragma unroll
        for (int ks = 0; ks < 2; ks++) {
            bf16x8 af[4], bfr[4];
#pragma unroll
            for (int mi = 0; mi < 4; mi++)
                af[mi] = *(const bf16x8*)(as + ((wr * 4 + mi) * 2 + ks) * 1024 + lane * 16);
#pragma unroll
            for (int ni = 0; ni < 4; ni++)
                bfr[ni] = *(const bf16x8*)(bs + ((wc * 4 + ni) * 2 + ks) * 1024 + lane * 16);
#pragma unroll
            for (int mi = 0; mi < 4; mi++)
#pragma unroll
                for (int ni = 0; ni < 4; ni++)
                    acc[mi][ni] = __builtin_amdgcn_mfma_f32_16x16x32_bf16(af[mi], bfr[ni], acc[mi][ni], 0, 0, 0);
        }
        __syncthreads();   // drains stage(t+1) loads; guards buf[cur] reuse next iter
        cur ^= 1;
    }

    // epilogue: C/D layout col = lane&15, row = (lane>>4)*4 + reg
    int wrow = m_base + wr * 64;
    int wcol = n_base + wc * 64;
    float bv[4];
    float4 lb0[4], lb1[4];
#pragma unroll
    for (int ni = 0; ni < 4; ni++) {
        int n = wcol + ni * 16 + l15;
        bv[ni] = bias[n];
        lb0[ni] = *(const float4*)(loraB + (size_t)n * 8);
        lb1[ni] = *(const float4*)(loraB + (size_t)n * 8 + 4);
    }
#pragma unroll
    for (int mi = 0; mi < 4; mi++) {
#pragma unroll
        for (int r = 0; r < 4; r++) {
            int m = wrow + mi * 16 + lhi * 4 + r;
            float4 xa0 = *(const float4*)(xa + (size_t)m * 8);
            float4 xa1 = *(const float4*)(xa + (size_t)m * 8 + 4);
#pragma unroll
            for (int ni = 0; ni < 4; ni++) {
                int n = wcol + ni * 16 + l15;
                float lora = xa0.x * lb0[ni].x + xa0.y * lb0[ni].y + xa0.z * lb0[ni].z + xa0.w * lb0[ni].w
                           + xa1.x * lb1[ni].x + xa1.y * lb1[ni].y + xa1.z * lb1[ni].z + xa1.w * lb1[ni].w;
                out[(size_t)m * N_DIM + n] = acc[mi][ni][r] + bv[ni] + lora;
            }
        }
    }
}

// ---------------- fallback (ws too small): correct but slow ----------------
__global__ void fallback_kernel(const float* __restrict__ x, const int* __restrict__ ids,
                                const float* __restrict__ W, const float* __restrict__ b,
                                const float* __restrict__ A, const float* __restrict__ B8,
                                float* __restrict__ out) {
    __shared__ float xs[K_DIM];
    __shared__ float xa_s[8];
    int row = blockIdx.y;
    int t = threadIdx.x;
    const float* xr = x + (size_t)row * K_DIM;
    for (int k = t; k < K_DIM; k += 256) xs[k] = xr[k];
    __syncthreads();
    if (t < 8) {
        float s = 0.f;
        for (int k = 0; k < K_DIM; k++) s += xs[k] * A[t * K_DIM + k];
        xa_s[t] = (ids[row] == 7) ? s * 2.0f : 0.0f;
    }
    __syncthreads();
    int col = blockIdx.x * 256 + t;
    const float* wr = W + (size_t)col * K_DIM;
    float acc = 0.f;
    for (int k = 0; k < K_DIM; k++) acc += xs[k] * wr[k];
    float lora = 0.f;
#pragma unroll
    for (int rr = 0; rr < 8; rr++) lora += xa_s[rr] * B8[col * 8 + rr];
    out[(size_t)row * N_DIM + col] = acc + b[col] + lora;
}

extern "C" void kernel_launch(void* const* d_in, const int* in_sizes, int n_in,
                              void* d_out, int out_size, void* d_ws, size_t ws_size,
                              hipStream_t stream) {
    const float* x   = (const float*)d_in[0];
    const int*   ids = (const int*)d_in[1];
    const float* W   = (const float*)d_in[2];
    const float* b   = (const float*)d_in[3];
    const float* lA  = (const float*)d_in[4];
    const float* lB  = (const float*)d_in[5];
    float* out = (float*)d_out;

    size_t wb_bytes = (size_t)N_DIM * K_DIM * 2;          // 32 MiB
    size_t xb_bytes = (size_t)M_DIM * K_DIM * 2;          // 128 MiB
    size_t xa_bytes = (size_t)M_DIM * 8 * 4;              // 0.5 MiB

    if (ws_size >= wb_bytes + xb_bytes + xa_bytes) {
        __hip_bfloat16* Wb = (__hip_bfloat16*)d_ws;
        __hip_bfloat16* Xb = (__hip_bfloat16*)((char*)d_ws + wb_bytes);
        float* xa = (float*)((char*)d_ws + wb_bytes + xb_bytes);

        cvt_f32_bf16<<<1024, 256, 0, stream>>>(W, Wb, (int)((size_t)N_DIM * K_DIM / 8));
        cvt_f32_bf16<<<2048, 256, 0, stream>>>(x, Xb, (int)((size_t)M_DIM * K_DIM / 8));
        compute_xa<<<M_DIM / 64, 256, 0, stream>>>(Xb, ids, lA, xa);
        gemm_bias_lora<<<(M_DIM / BM) * (N_DIM / BN), 256, 0, stream>>>(Xb, Wb, b, xa, lB, out);
    } else {
        fallback_kernel<<<dim3(N_DIM / 256, M_DIM), 256, 0, stream>>>(x, ids, W, b, lA, lB, out);
    }
}

// Round 3
// 759.492 us; speedup vs baseline: 1.9662x; 1.9662x over previous
//
#include <hip/hip_runtime.h>
#include <hip/hip_bf16.h>
#include <stdint.h>

// ConditionalLoRALinear: out = x@W^T + b + mask*(2*(x@A^T)@B^T)
// M=16384, K=4096, N=4096, R=8. bf16 MFMA path.
// R3: 256x256 tile, BK=32, 3-buffer LDS ring (96 KiB), counted vmcnt(4) +
//     raw s_barrier (never drain in main loop), fragment-major conflict-free
//     LDS, 8 waves (2Mx4N), setprio around MFMA clusters, XCD swizzle.

typedef __attribute__((ext_vector_type(8))) __bf16 bf16x8;
typedef __attribute__((ext_vector_type(4))) float f32x4;

#define M_DIM 16384
#define K_DIM 4096
#define N_DIM 4096
#define BM 256
#define BN 256
#define BK 32
#define NT (K_DIM / BK)   // 128

// ---------------- f32 -> bf16 conversion ----------------
__global__ void cvt_f32_bf16(const float* __restrict__ in, __hip_bfloat16* __restrict__ out, int n8) {
    int i = blockIdx.x * blockDim.x + threadIdx.x;
    int stride = gridDim.x * blockDim.x;
    for (; i < n8; i += stride) {
        const float4* p = (const float4*)(in + (size_t)i * 8);
        float4 v0 = p[0], v1 = p[1];
        bf16x8 o;
        o[0] = (__bf16)v0.x; o[1] = (__bf16)v0.y; o[2] = (__bf16)v0.z; o[3] = (__bf16)v0.w;
        o[4] = (__bf16)v1.x; o[5] = (__bf16)v1.y; o[6] = (__bf16)v1.z; o[7] = (__bf16)v1.w;
        *(bf16x8*)((__hip_bfloat16*)out + (size_t)i * 8) = o;
    }
}

// ---------------- xa[m][r] = 2 * mask(m) * dot(x[m], A[r]) ----------------
__global__ void compute_xa(const __hip_bfloat16* __restrict__ Xb,
                           const int* __restrict__ ids,
                           const float* __restrict__ A,   // [8, K]
                           float* __restrict__ xa) {
    int t = threadIdx.x;
    int r = t & 63;
    int kq = t >> 6;
    int row = blockIdx.x * 64 + r;
    const __hip_bfloat16* xrow = Xb + (size_t)row * K_DIM + kq * 1024;
    float acc[8] = {0.f, 0.f, 0.f, 0.f, 0.f, 0.f, 0.f, 0.f};
    for (int i = 0; i < 128; i++) {
        bf16x8 xv = *(const bf16x8*)(xrow + i * 8);
        int kk = kq * 1024 + i * 8;
#pragma unroll
        for (int rr = 0; rr < 8; rr++) {
            const float* ap = A + rr * K_DIM + kk;
            float4 a0 = *(const float4*)ap;
            float4 a1 = *(const float4*)(ap + 4);
            acc[rr] += (float)xv[0] * a0.x + (float)xv[1] * a0.y + (float)xv[2] * a0.z + (float)xv[3] * a0.w
                     + (float)xv[4] * a1.x + (float)xv[5] * a1.y + (float)xv[6] * a1.z + (float)xv[7] * a1.w;
        }
    }
    __shared__ float red[4][64][8];
#pragma unroll
    for (int rr = 0; rr < 8; rr++) red[kq][r][rr] = acc[rr];
    __syncthreads();
    if (t < 64) {
        int rowg = blockIdx.x * 64 + t;
        float gate = (ids[rowg] == 7) ? 2.0f : 0.0f;
#pragma unroll
        for (int rr = 0; rr < 8; rr++) {
            float s = (red[0][t][rr] + red[1][t][rr]) + (red[2][t][rr] + red[3][t][rr]);
            xa[(size_t)rowg * 8 + rr] = s * gate;
        }
    }
}

// ---------------- main GEMM ----------------
__device__ __forceinline__ void gload_lds16(const void* g, void* l) {
    __builtin_amdgcn_global_load_lds(
        (const __attribute__((address_space(1))) unsigned int*)g,
        (__attribute__((address_space(3))) unsigned int*)l, 16, 0, 0);
}

// LDS per buffer: A 16 KiB (16 chunks of 1 KiB) + B 16 KiB. Chunk g holds rows
// [g*16,g*16+16) x k[0,32): byte l*16 = row g*16+(l&15), k-elems (l>>4)*8..+8
// == exactly the 16x16x32 MFMA fragment for lane l -> ds_read_b128 at lane*16,
// zero bank conflicts; per-lane global source implements the permutation.
__global__ __launch_bounds__(512, 2) void gemm_bias_lora(
    const __hip_bfloat16* __restrict__ Xb,   // [M, K]
    const __hip_bfloat16* __restrict__ Wb,   // [N, K]
    const float* __restrict__ bias,          // [N]
    const float* __restrict__ xa,            // [M, 8] pre-scaled & gated
    const float* __restrict__ loraB,         // [N, 8]
    float* __restrict__ out) {
    __shared__ char smem[3][32768];          // 96 KiB: 3 x (A 16K | B 16K)

    int tid = threadIdx.x;
    // XCD-bijective swizzle: nwg = 1024 = 8*128
    int bid = blockIdx.x;
    int swz = (bid & 7) * 128 + (bid >> 3);
    int n_tile = swz & 15;                   // N/BN = 16
    int m_tile = swz >> 4;                   // M/BM = 64
    int m_base = m_tile * BM, n_base = n_tile * BN;
    int wave = tid >> 6, lane = tid & 63;
    int wr = wave >> 2, wc = wave & 3;       // 2M x 4N wave grid
    int l15 = lane & 15, lhi = lane >> 4;

    f32x4 acc[8][4] = {};

    const char* Abase = (const char*)(Xb + (size_t)m_base * K_DIM);
    const char* Bbase = (const char*)(Wb + (size_t)n_base * K_DIM);

    // 4 gload_lds16 per thread per step (A:2, B:2)
    auto stage = [&](int kt, int buf) {
        char* as = smem[buf];
        char* bs = smem[buf] + 16384;
        size_t kb = (size_t)kt * (BK * 2) + lhi * 16;   // k-byte offset within row
#pragma unroll
        for (int j = 0; j < 2; j++) {
            int c = wave + j * 8;                        // chunk [0,16)
            size_t src = (size_t)(c * 16 + l15) * (K_DIM * 2) + kb;
            gload_lds16(Abase + src, as + c * 1024 + lane * 16);
        }
#pragma unroll
        for (int j = 0; j < 2; j++) {
            int c = wave + j * 8;
            size_t src = (size_t)(c * 16 + l15) * (K_DIM * 2) + kb;
            gload_lds16(Bbase + src, bs + c * 1024 + lane * 16);
        }
    };

    // prologue: fill buf0, buf1; retire buf0's loads, leave buf1's in flight
    stage(0, 0);
    stage(1, 1);
    asm volatile("s_waitcnt vmcnt(4)" ::: "memory");
    __builtin_amdgcn_s_barrier();

    int cur = 0;
    for (int s = 0; s < NT; s++) {
        const char* as = smem[cur];
        const char* bs = smem[cur] + 16384;

        bf16x8 bfr[4];
#pragma unroll
        for (int ni = 0; ni < 4; ni++)
            bfr[ni] = *(const bf16x8*)(bs + (wc * 4 + ni) * 1024 + lane * 16);
        bf16x8 af[8];
#pragma unroll
        for (int mi = 0; mi < 4; mi++)
            af[mi] = *(const bf16x8*)(as + (wr * 8 + mi) * 1024 + lane * 16);

        // prefetch K-tile s+2 into the buffer freed at end of step s-1
        if (s + 2 < NT) {
            int b2 = cur + 2; if (b2 >= 3) b2 -= 3;
            stage(s + 2, b2);
        }

        __builtin_amdgcn_s_setprio(1);
#pragma unroll
        for (int mi = 0; mi < 4; mi++)
#pragma unroll
            for (int ni = 0; ni < 4; ni++)
                acc[mi][ni] = __builtin_amdgcn_mfma_f32_16x16x32_bf16(af[mi], bfr[ni], acc[mi][ni], 0, 0, 0);
        __builtin_amdgcn_s_setprio(0);

#pragma unroll
        for (int mi = 4; mi < 8; mi++)
            af[mi] = *(const bf16x8*)(as + (wr * 8 + mi) * 1024 + lane * 16);

        __builtin_amdgcn_s_setprio(1);
#pragma unroll
        for (int mi = 4; mi < 8; mi++)
#pragma unroll
            for (int ni = 0; ni < 4; ni++)
                acc[mi][ni] = __builtin_amdgcn_mfma_f32_16x16x32_bf16(af[mi], bfr[ni], acc[mi][ni], 0, 0, 0);
        __builtin_amdgcn_s_setprio(0);

        // counted wait: retire step s-1's 4 loads (buffer read next step),
        // leave this step's 4 in flight. Drain only in the last 2 steps.
        if (s < NT - 2) asm volatile("s_waitcnt vmcnt(4)" ::: "memory");
        else            asm volatile("s_waitcnt vmcnt(0)" ::: "memory");
        __builtin_amdgcn_s_barrier();
        asm volatile("" ::: "memory");

        cur = (cur + 1 == 3) ? 0 : cur + 1;
    }

    // epilogue: C/D layout col = lane&15, row = (lane>>4)*4 + reg
    int wrow = m_base + wr * 128;
    int wcol = n_base + wc * 64;
    float bv[4];
    float4 lb0[4], lb1[4];
#pragma unroll
    for (int ni = 0; ni < 4; ni++) {
        int n = wcol + ni * 16 + l15;
        bv[ni] = bias[n];
        lb0[ni] = *(const float4*)(loraB + (size_t)n * 8);
        lb1[ni] = *(const float4*)(loraB + (size_t)n * 8 + 4);
    }
#pragma unroll
    for (int mi = 0; mi < 8; mi++) {
#pragma unroll
        for (int r = 0; r < 4; r++) {
            int m = wrow + mi * 16 + lhi * 4 + r;
            float4 xa0 = *(const float4*)(xa + (size_t)m * 8);
            float4 xa1 = *(const float4*)(xa + (size_t)m * 8 + 4);
#pragma unroll
            for (int ni = 0; ni < 4; ni++) {
                int n = wcol + ni * 16 + l15;
                float lora = xa0.x * lb0[ni].x + xa0.y * lb0[ni].y + xa0.z * lb0[ni].z + xa0.w * lb0[ni].w
                           + xa1.x * lb1[ni].x + xa1.y * lb1[ni].y + xa1.z * lb1[ni].z + xa1.w * lb1[ni].w;
                out[(size_t)m * N_DIM + n] = acc[mi][ni][r] + bv[ni] + lora;
            }
        }
    }
}

// ---------------- fallback (ws too small): correct but slow ----------------
__global__ void fallback_kernel(const float* __restrict__ x, const int* __restrict__ ids,
                                const float* __restrict__ W, const float* __restrict__ b,
                                const float* __restrict__ A, const float* __restrict__ B8,
                                float* __restrict__ out) {
    __shared__ float xs[K_DIM];
    __shared__ float xa_s[8];
    int row = blockIdx.y;
    int t = threadIdx.x;
    const float* xr = x + (size_t)row * K_DIM;
    for (int k = t; k < K_DIM; k += 256) xs[k] = xr[k];
    __syncthreads();
    if (t < 8) {
        float s = 0.f;
        for (int k = 0; k < K_DIM; k++) s += xs[k] * A[t * K_DIM + k];
        xa_s[t] = (ids[row] == 7) ? s * 2.0f : 0.0f;
    }
    __syncthreads();
    int col = blockIdx.x * 256 + t;
    const float* wr = W + (size_t)col * K_DIM;
    float acc = 0.f;
    for (int k = 0; k < K_DIM; k++) acc += xs[k] * wr[k];
    float lora = 0.f;
#pragma unroll
    for (int rr = 0; rr < 8; rr++) lora += xa_s[rr] * B8[col * 8 + rr];
    out[(size_t)row * N_DIM + col] = acc + b[col] + lora;
}

extern "C" void kernel_launch(void* const* d_in, const int* in_sizes, int n_in,
                              void* d_out, int out_size, void* d_ws, size_t ws_size,
                              hipStream_t stream) {
    const float* x   = (const float*)d_in[0];
    const int*   ids = (const int*)d_in[1];
    const float* W   = (const float*)d_in[2];
    const float* b   = (const float*)d_in[3];
    const float* lA  = (const float*)d_in[4];
    const float* lB  = (const float*)d_in[5];
    float* out = (float*)d_out;

    size_t wb_bytes = (size_t)N_DIM * K_DIM * 2;          // 32 MiB
    size_t xb_bytes = (size_t)M_DIM * K_DIM * 2;          // 128 MiB
    size_t xa_bytes = (size_t)M_DIM * 8 * 4;              // 0.5 MiB

    if (ws_size >= wb_bytes + xb_bytes + xa_bytes) {
        __hip_bfloat16* Wb = (__hip_bfloat16*)d_ws;
        __hip_bfloat16* Xb = (__hip_bfloat16*)((char*)d_ws + wb_bytes);
        float* xa = (float*)((char*)d_ws + wb_bytes + xb_bytes);

        cvt_f32_bf16<<<1024, 256, 0, stream>>>(W, Wb, (int)((size_t)N_DIM * K_DIM / 8));
        cvt_f32_bf16<<<2048, 256, 0, stream>>>(x, Xb, (int)((size_t)M_DIM * K_DIM / 8));
        compute_xa<<<M_DIM / 64, 256, 0, stream>>>(Xb, ids, lA, xa);
        gemm_bias_lora<<<(M_DIM / BM) * (N_DIM / BN), 512, 0, stream>>>(Xb, Wb, b, xa, lB, out);
    } else {
        fallback_kernel<<<dim3(N_DIM / 256, M_DIM), 256, 0, stream>>>(x, ids, W, b, lA, lB, out);
    }
}